// Round 4
// baseline (211.620 us; speedup 1.0000x reference)
//
#include <hip/hip_runtime.h>

// IoU mean over B=1e6 x NBOX=6 midpoint-format box pairs, sentinel-masked.
// Streaming reduction: 192 MB logical in, 1 float out.
// R0: 1024 blk, MLP=2              -> iou_partial 66.6 us, 1.44 TB/s HBM
// R1: 2048 blk (100% waves), MLP=8 -> 68.0 us. Wall insensitive to occ/MLP.
// R3: nontemporal loads -> iou_partial < 56 us. (Measured under OLD
//     grid-stride structure; mechanism never pinned down.)
// R4: exact-cover grid, unroll-6, split accumulators -> 190 us total.
// R5: rcp_f32 instead of IEEE fdiv. Verified 189.7 us.
// R6/R7: infra failures. No data.
// R8: clean re-baseline 190.6 us; fills 6.65-6.74 TB/s; back-solved
//     iou_partial ~55 us = ~3.5 TB/s read.
// R9: contiguous per-block chunks (1024 blk x ~5860 pairs, unroll-8):
//     188.8 us = NEUTRAL. DRAM page-locality theory FALSIFIED; channel
//     interleave makes layout moot. Remaining untested read-path
//     variable: the nt flag itself. Note: poison fills drain fully to
//     HBM within their own dispatch (WRITE_SIZE=384MB), so the original
//     "nt avoids writeback interference" story is dead; nt may in fact
//     be CAPPING read service (no L2 buffering / reduced priority).
// R10 (this round): single-variable A/B — drop nt, plain global loads,
//     structure otherwise byte-identical to R9.
//     Pre-committed: ~172-180 -> keep; ~195-200 -> revert, nt-win real,
//     3.5 TB/s is the nt-read equilibrium; ~185-192 -> nt cosmetic,
//     pure-read cap is structural, roofline case strengthens.

#define BLOCKS 1024
#define THREADS 256
#define UNROLL 8

typedef float vfloat4 __attribute__((ext_vector_type(4)));

__device__ __forceinline__ vfloat4 ld4(const float4* p) {
    return *(const vfloat4*)p;   // plain global_load_dwordx4, L2-allocating
}

__device__ __forceinline__ void iou_accum(vfloat4 p, vfloat4 t,
                                          float& s_iou, float& s_cnt) {
    // valid iff truth row is not the sentinel [-1,-1,-1,-1]; branchless mask
    float v = (t.x == -1.0f && t.y == -1.0f &&
               t.z == -1.0f && t.w == -1.0f) ? 0.0f : 1.0f;

    float p_x1 = p.x - p.z * 0.5f;
    float p_y1 = p.y - p.w * 0.5f;
    float p_x2 = p.x + p.z * 0.5f;
    float p_y2 = p.y + p.w * 0.5f;
    float t_x1 = t.x - t.z * 0.5f;
    float t_y1 = t.y - t.w * 0.5f;
    float t_x2 = t.x + t.z * 0.5f;
    float t_y2 = t.y + t.w * 0.5f;

    float x1 = fmaxf(p_x1, t_x1);
    float y1 = fmaxf(p_y1, t_y1);
    float x2 = fminf(p_x2, t_x2);
    float y2 = fminf(p_y2, t_y2);

    float inter  = fmaxf(x2 - x1, 0.0f) * fmaxf(y2 - y1, 0.0f);
    float area_p = fabsf((p_x2 - p_x1) * (p_y2 - p_y1));
    float area_t = fabsf((t_x2 - t_x1) * (t_y2 - t_y1));

    // fast reciprocal: v_rcp_f32 (rel err ~1e-7) instead of IEEE fdiv
    float denom = area_p + area_t - inter + 1e-6f;
    s_iou += v * inter * __builtin_amdgcn_rcpf(denom);
    s_cnt += v;
}

__global__ __launch_bounds__(THREADS) void iou_partial(
    const float4* __restrict__ pred,
    const float4* __restrict__ truth,
    float* __restrict__ partials,   // [BLOCKS][2]: {sum_iou, sum_valid}
    int n)                          // number of (b,box) pairs
{
    // contiguous per-block chunk: block b streams [base, end) sequentially
    const int chunk = (n + BLOCKS - 1) / BLOCKS;
    const int base  = blockIdx.x * chunk;
    const int end   = min(base + chunk, n);

    // two independent accumulator pairs to break the rcp->add serial chain
    float s_iou0 = 0.0f, s_cnt0 = 0.0f;
    float s_iou1 = 0.0f, s_cnt1 = 0.0f;

    int i = base + threadIdx.x;
    // unroll x8: 16 independent loads in flight; consecutive steps are
    // 4 KB apart -> each block is one long sequential stream per array
    for (; i + (UNROLL - 1) * THREADS < end; i += UNROLL * THREADS) {
        vfloat4 p0 = ld4(&pred[i]);
        vfloat4 p1 = ld4(&pred[i + 1 * THREADS]);
        vfloat4 p2 = ld4(&pred[i + 2 * THREADS]);
        vfloat4 p3 = ld4(&pred[i + 3 * THREADS]);
        vfloat4 p4 = ld4(&pred[i + 4 * THREADS]);
        vfloat4 p5 = ld4(&pred[i + 5 * THREADS]);
        vfloat4 p6 = ld4(&pred[i + 6 * THREADS]);
        vfloat4 p7 = ld4(&pred[i + 7 * THREADS]);
        vfloat4 t0 = ld4(&truth[i]);
        vfloat4 t1 = ld4(&truth[i + 1 * THREADS]);
        vfloat4 t2 = ld4(&truth[i + 2 * THREADS]);
        vfloat4 t3 = ld4(&truth[i + 3 * THREADS]);
        vfloat4 t4 = ld4(&truth[i + 4 * THREADS]);
        vfloat4 t5 = ld4(&truth[i + 5 * THREADS]);
        vfloat4 t6 = ld4(&truth[i + 6 * THREADS]);
        vfloat4 t7 = ld4(&truth[i + 7 * THREADS]);
        iou_accum(p0, t0, s_iou0, s_cnt0);
        iou_accum(p1, t1, s_iou1, s_cnt1);
        iou_accum(p2, t2, s_iou0, s_cnt0);
        iou_accum(p3, t3, s_iou1, s_cnt1);
        iou_accum(p4, t4, s_iou0, s_cnt0);
        iou_accum(p5, t5, s_iou1, s_cnt1);
        iou_accum(p6, t6, s_iou0, s_cnt0);
        iou_accum(p7, t7, s_iou1, s_cnt1);
    }
    for (; i < end; i += THREADS) {
        vfloat4 p = ld4(&pred[i]);
        vfloat4 t = ld4(&truth[i]);
        iou_accum(p, t, s_iou0, s_cnt0);
    }

    float s_iou = s_iou0 + s_iou1;
    float s_cnt = s_cnt0 + s_cnt1;

    // wave (64-lane) shuffle reduction
    for (int off = 32; off > 0; off >>= 1) {
        s_iou += __shfl_down(s_iou, off, 64);
        s_cnt += __shfl_down(s_cnt, off, 64);
    }

    __shared__ float lds_iou[THREADS / 64];
    __shared__ float lds_cnt[THREADS / 64];
    int lane = threadIdx.x & 63;
    int wave = threadIdx.x >> 6;
    if (lane == 0) {
        lds_iou[wave] = s_iou;
        lds_cnt[wave] = s_cnt;
    }
    __syncthreads();

    if (threadIdx.x == 0) {
        float a = 0.0f, b = 0.0f;
        #pragma unroll
        for (int w = 0; w < THREADS / 64; ++w) {
            a += lds_iou[w];
            b += lds_cnt[w];
        }
        partials[2 * blockIdx.x]     = a;
        partials[2 * blockIdx.x + 1] = b;
    }
}

__global__ __launch_bounds__(THREADS) void iou_finalize(
    const float* __restrict__ partials, int nblocks, float* __restrict__ out)
{
    float s_iou = 0.0f;
    float s_cnt = 0.0f;
    for (int i = threadIdx.x; i < nblocks; i += blockDim.x) {
        s_iou += partials[2 * i];
        s_cnt += partials[2 * i + 1];
    }
    for (int off = 32; off > 0; off >>= 1) {
        s_iou += __shfl_down(s_iou, off, 64);
        s_cnt += __shfl_down(s_cnt, off, 64);
    }
    __shared__ float lds_iou[THREADS / 64];
    __shared__ float lds_cnt[THREADS / 64];
    int lane = threadIdx.x & 63;
    int wave = threadIdx.x >> 6;
    if (lane == 0) {
        lds_iou[wave] = s_iou;
        lds_cnt[wave] = s_cnt;
    }
    __syncthreads();
    if (threadIdx.x == 0) {
        float a = 0.0f, b = 0.0f;
        #pragma unroll
        for (int w = 0; w < THREADS / 64; ++w) {
            a += lds_iou[w];
            b += lds_cnt[w];
        }
        // final divide runs once; keep it exact
        out[0] = (b > 0.0f) ? (a / fmaxf(b, 1.0f)) : 0.0f;
    }
}

extern "C" void kernel_launch(void* const* d_in, const int* in_sizes, int n_in,
                              void* d_out, int out_size, void* d_ws, size_t ws_size,
                              hipStream_t stream) {
    const float4* pred  = (const float4*)d_in[0];
    const float4* truth = (const float4*)d_in[1];
    float* out = (float*)d_out;
    float* partials = (float*)d_ws;   // BLOCKS*2 floats, overwritten every call

    int n_pairs = in_sizes[0] / 4;    // B * NBOX

    iou_partial<<<BLOCKS, THREADS, 0, stream>>>(pred, truth, partials, n_pairs);
    iou_finalize<<<1, THREADS, 0, stream>>>(partials, BLOCKS, out);
}

// Round 5
// 189.884 us; speedup vs baseline: 1.1145x; 1.1145x over previous
//
#include <hip/hip_runtime.h>

// IoU mean over B=1e6 x NBOX=6 midpoint-format box pairs, sentinel-masked.
// Streaming reduction: 192 MB logical in, 1 float out.
// R0: 1024 blk, MLP=2, plain       -> iou_partial 66.6 us, ~2.9 TB/s
// R1: 2048 blk (100% waves), MLP=8 -> 68.0 us. Occ/MLP insensitive (plain).
// R3: nontemporal loads            -> iou_partial ~53 us (3.6 TB/s).
// R4/R5: exact-cover grid, unroll, rcp_f32 -> 189.7 us verified.
// R8: re-baseline 190.6 us; harness fills 6.65-6.74 TB/s (pure write).
// R9: contiguous per-block chunks: 188.8 us NEUTRAL -> DRAM page-locality
//     theory falsified; layout moot under channel interleave.
// R10: nt dropped (plain loads) A/B: 211.6 us, iou_partial=75.9 us,
//     FETCH=94 MB (half served by L3!) yet SLOWER -> the limiter is the
//     read/request path (L2 allocation / TCC outstanding-read capacity),
//     not DRAM. L3-hit service ~1.9 TB/s < HBM-miss path. nt-win REAL.
//     3.6 TB/s is the highest pure-read rate on record for this part
//     (copy ubench ~3.15 R; RMSNorm ~2.45 R; pure write 6.8).
// R11 (this round): restore nt (mandatory revert) + the one cheap probe
//     left on the request-capacity model: BLOCKS 1024->2048 (8 blk/CU,
//     100% wave occupancy, 2x independent request sources).
//     Predict: neutral ~187-191 (cap is TCC/fabric -> ROOFLINE next
//     round) or iou_partial -> 42-46 us, total ~176-182 (per-wave
//     request-depth was binding).

#define BLOCKS 2048
#define THREADS 256
#define UNROLL 8

typedef float vfloat4 __attribute__((ext_vector_type(4)));

__device__ __forceinline__ vfloat4 nt_load4(const float4* p) {
    return __builtin_nontemporal_load((const vfloat4*)p);
}

__device__ __forceinline__ void iou_accum(vfloat4 p, vfloat4 t,
                                          float& s_iou, float& s_cnt) {
    // valid iff truth row is not the sentinel [-1,-1,-1,-1]; branchless mask
    float v = (t.x == -1.0f && t.y == -1.0f &&
               t.z == -1.0f && t.w == -1.0f) ? 0.0f : 1.0f;

    float p_x1 = p.x - p.z * 0.5f;
    float p_y1 = p.y - p.w * 0.5f;
    float p_x2 = p.x + p.z * 0.5f;
    float p_y2 = p.y + p.w * 0.5f;
    float t_x1 = t.x - t.z * 0.5f;
    float t_y1 = t.y - t.w * 0.5f;
    float t_x2 = t.x + t.z * 0.5f;
    float t_y2 = t.y + t.w * 0.5f;

    float x1 = fmaxf(p_x1, t_x1);
    float y1 = fmaxf(p_y1, t_y1);
    float x2 = fminf(p_x2, t_x2);
    float y2 = fminf(p_y2, t_y2);

    float inter  = fmaxf(x2 - x1, 0.0f) * fmaxf(y2 - y1, 0.0f);
    float area_p = fabsf((p_x2 - p_x1) * (p_y2 - p_y1));
    float area_t = fabsf((t_x2 - t_x1) * (t_y2 - t_y1));

    // fast reciprocal: v_rcp_f32 (rel err ~1e-7) instead of IEEE fdiv
    float denom = area_p + area_t - inter + 1e-6f;
    s_iou += v * inter * __builtin_amdgcn_rcpf(denom);
    s_cnt += v;
}

__global__ __launch_bounds__(THREADS) void iou_partial(
    const float4* __restrict__ pred,
    const float4* __restrict__ truth,
    float* __restrict__ partials,   // [BLOCKS][2]: {sum_iou, sum_valid}
    int n)                          // number of (b,box) pairs
{
    // contiguous per-block chunk: block b streams [base, end) sequentially
    const int chunk = (n + BLOCKS - 1) / BLOCKS;
    const int base  = blockIdx.x * chunk;
    const int end   = min(base + chunk, n);

    // two independent accumulator pairs to break the rcp->add serial chain
    float s_iou0 = 0.0f, s_cnt0 = 0.0f;
    float s_iou1 = 0.0f, s_cnt1 = 0.0f;

    int i = base + threadIdx.x;
    // unroll x8: 16 independent nt loads in flight per thread
    for (; i + (UNROLL - 1) * THREADS < end; i += UNROLL * THREADS) {
        vfloat4 p0 = nt_load4(&pred[i]);
        vfloat4 p1 = nt_load4(&pred[i + 1 * THREADS]);
        vfloat4 p2 = nt_load4(&pred[i + 2 * THREADS]);
        vfloat4 p3 = nt_load4(&pred[i + 3 * THREADS]);
        vfloat4 p4 = nt_load4(&pred[i + 4 * THREADS]);
        vfloat4 p5 = nt_load4(&pred[i + 5 * THREADS]);
        vfloat4 p6 = nt_load4(&pred[i + 6 * THREADS]);
        vfloat4 p7 = nt_load4(&pred[i + 7 * THREADS]);
        vfloat4 t0 = nt_load4(&truth[i]);
        vfloat4 t1 = nt_load4(&truth[i + 1 * THREADS]);
        vfloat4 t2 = nt_load4(&truth[i + 2 * THREADS]);
        vfloat4 t3 = nt_load4(&truth[i + 3 * THREADS]);
        vfloat4 t4 = nt_load4(&truth[i + 4 * THREADS]);
        vfloat4 t5 = nt_load4(&truth[i + 5 * THREADS]);
        vfloat4 t6 = nt_load4(&truth[i + 6 * THREADS]);
        vfloat4 t7 = nt_load4(&truth[i + 7 * THREADS]);
        iou_accum(p0, t0, s_iou0, s_cnt0);
        iou_accum(p1, t1, s_iou1, s_cnt1);
        iou_accum(p2, t2, s_iou0, s_cnt0);
        iou_accum(p3, t3, s_iou1, s_cnt1);
        iou_accum(p4, t4, s_iou0, s_cnt0);
        iou_accum(p5, t5, s_iou1, s_cnt1);
        iou_accum(p6, t6, s_iou0, s_cnt0);
        iou_accum(p7, t7, s_iou1, s_cnt1);
    }
    for (; i < end; i += THREADS) {
        vfloat4 p = nt_load4(&pred[i]);
        vfloat4 t = nt_load4(&truth[i]);
        iou_accum(p, t, s_iou0, s_cnt0);
    }

    float s_iou = s_iou0 + s_iou1;
    float s_cnt = s_cnt0 + s_cnt1;

    // wave (64-lane) shuffle reduction
    for (int off = 32; off > 0; off >>= 1) {
        s_iou += __shfl_down(s_iou, off, 64);
        s_cnt += __shfl_down(s_cnt, off, 64);
    }

    __shared__ float lds_iou[THREADS / 64];
    __shared__ float lds_cnt[THREADS / 64];
    int lane = threadIdx.x & 63;
    int wave = threadIdx.x >> 6;
    if (lane == 0) {
        lds_iou[wave] = s_iou;
        lds_cnt[wave] = s_cnt;
    }
    __syncthreads();

    if (threadIdx.x == 0) {
        float a = 0.0f, b = 0.0f;
        #pragma unroll
        for (int w = 0; w < THREADS / 64; ++w) {
            a += lds_iou[w];
            b += lds_cnt[w];
        }
        partials[2 * blockIdx.x]     = a;
        partials[2 * blockIdx.x + 1] = b;
    }
}

__global__ __launch_bounds__(THREADS) void iou_finalize(
    const float* __restrict__ partials, int nblocks, float* __restrict__ out)
{
    float s_iou = 0.0f;
    float s_cnt = 0.0f;
    for (int i = threadIdx.x; i < nblocks; i += blockDim.x) {
        s_iou += partials[2 * i];
        s_cnt += partials[2 * i + 1];
    }
    for (int off = 32; off > 0; off >>= 1) {
        s_iou += __shfl_down(s_iou, off, 64);
        s_cnt += __shfl_down(s_cnt, off, 64);
    }
    __shared__ float lds_iou[THREADS / 64];
    __shared__ float lds_cnt[THREADS / 64];
    int lane = threadIdx.x & 63;
    int wave = threadIdx.x >> 6;
    if (lane == 0) {
        lds_iou[wave] = s_iou;
        lds_cnt[wave] = s_cnt;
    }
    __syncthreads();
    if (threadIdx.x == 0) {
        float a = 0.0f, b = 0.0f;
        #pragma unroll
        for (int w = 0; w < THREADS / 64; ++w) {
            a += lds_iou[w];
            b += lds_cnt[w];
        }
        // final divide runs once; keep it exact
        out[0] = (b > 0.0f) ? (a / fmaxf(b, 1.0f)) : 0.0f;
    }
}

extern "C" void kernel_launch(void* const* d_in, const int* in_sizes, int n_in,
                              void* d_out, int out_size, void* d_ws, size_t ws_size,
                              hipStream_t stream) {
    const float4* pred  = (const float4*)d_in[0];
    const float4* truth = (const float4*)d_in[1];
    float* out = (float*)d_out;
    float* partials = (float*)d_ws;   // BLOCKS*2 floats, overwritten every call

    int n_pairs = in_sizes[0] / 4;    // B * NBOX

    iou_partial<<<BLOCKS, THREADS, 0, stream>>>(pred, truth, partials, n_pairs);
    iou_finalize<<<1, THREADS, 0, stream>>>(partials, BLOCKS, out);
}